// Round 2
// baseline (173.907 us; speedup 1.0000x reference)
//
#include <hip/hip_runtime.h>
#include <math.h>

#define N       4096
#define NPARAM  15
#define IB      64          // i-rows per pairwise block (one per lane)

typedef float f32x2 __attribute__((ext_vector_type(2)));
typedef float f32x4 __attribute__((ext_vector_type(4)));

// Derived per-point params (rescaled so the O(n^2) loop is minimal):
//   o0 = t, o1 = ra, o2 = dec, o3 = psi
//   o4 = mc/30                        (mass_sim = rcp(1+|d o4|))
//   o5 = 220*0.01*log2(e)/msum       (freq_ov  = exp2(-|d o5|))
//   o6 = log2(dist)                   (dist_rat = exp2(-|d o6|), exact)
__device__ __forceinline__ void derive_params(const float* __restrict__ r, float* o) {
  float m1 = fmaf(r[0], 95.0f, 5.0f);
  float m2 = fmaf(r[1], 95.0f, 5.0f);
  float msum = m1 + m2;
  float mc30 = __builtin_amdgcn_exp2f(
      0.6f * __builtin_amdgcn_logf(m1 * m2)
      - 0.2f * __builtin_amdgcn_logf(msum)
      - 4.906890595608519f);
  o[0] = r[5];
  o[1] = r[3];
  o[2] = r[4];
  o[3] = r[7];
  o[4] = mc30;
  o[5] = 3.1739290899556993f * __builtin_amdgcn_rcpf(msum);
  o[6] = __builtin_amdgcn_logf(fmaf(r[2], 2950.0f, 50.0f));
  o[7] = 0.0f;
}

// One-shot derive: writes
//   Dpair[N/2][16]  pair-interleaved (t0,t1, ra0,ra1, dec0,dec1, psi0,psi1,
//                    mc0,mc1, f0,f1, d0,d1, pad,pad) -> 64B wave-uniform records
//   Di[N][8]        AoS copy for the per-lane i-side (2x dwordx4, coalesced)
__global__ __launch_bounds__(256) void derive_kernel(
    const float* __restrict__ p, float* __restrict__ Dpair,
    float* __restrict__ Di) {
  int j = blockIdx.x * 256 + threadIdx.x;
  float o[8];
  derive_params(p + (size_t)j * NPARAM, o);
  f32x4* di = (f32x4*)(Di + (size_t)j * 8);
  di[0] = f32x4{o[0], o[1], o[2], o[3]};
  di[1] = f32x4{o[4], o[5], o[6], 0.0f};
  float* dq = Dpair + (size_t)(j >> 1) * 16;
  int l = j & 1;
#pragma unroll
  for (int k = 0; k < 7; k++) dq[k * 2 + l] = o[k];
  if (l) { dq[14] = 0.0f; dq[15] = 0.0f; }
}

// Block: 64 i's (one per lane), 4 waves split JPB j's (JPB/4 each; 2 j's per
// iteration via packed-f32 math). j-operands are wave-uniform -> scalar-path
// loads, zero LDS in the hot loop, zero staging sync. LDS-reduce at the end,
// then one coalesced store of 64x8 partials to out[jb][i][8] (PARTIAL) or
// atomicAdd (fallback).
template <int NJT, bool PARTIAL>
__global__ __launch_bounds__(256, 8) void pairwise_kernel(
    const float* __restrict__ Dpair, const float* __restrict__ Di,
    float* __restrict__ out) {
  constexpr int JPB = N / NJT;      // j's per block
  constexpr int JPW = JPB / 4;      // j's per wave
  __shared__ float sacc[4 * IB * 8];
  int t    = threadIdx.x;
  int ib   = blockIdx.x;
  int jb   = blockIdx.y;
  int w    = __builtin_amdgcn_readfirstlane(t >> 6);  // wave id (uniform)
  int lane = t & 63;
  int i    = ib * IB + lane;

  // my i-point (pre-derived, coalesced vector load)
  const f32x4* di = (const f32x4*)(Di + (size_t)i * 8);
  f32x4 piA = di[0];
  f32x4 piB = di[1];
  float ti = piA.x, rai = piA.y, deci = piA.z, psii = piA.w;
  float mci = piB.x, fi = piB.y, dsi = piB.z;

  // wave w handles j-pairs [jb*JPB/2 + w*JPW/2, +JPW/2): uniform address
  const float* dp = Dpair + ((size_t)jb * (JPB / 2) + (size_t)w * (JPW / 2)) * 16;

  f32x2 a_dt = {0.f, 0.f}, a_sky = {0.f, 0.f}, a_ms = {0.f, 0.f},
        a_fo = {0.f, 0.f}, a_dr = {0.f, 0.f}, a_ps = {0.f, 0.f},
        a_ra = {0.f, 0.f}, a_dc = {0.f, 0.f};

#pragma unroll
  for (int q = 0; q < JPW / 2; q++) {
    const f32x4* c4 = (const f32x4*)(dp + (size_t)q * 16);
    f32x4 v0 = c4[0];   // t0,t1, ra0,ra1
    f32x4 v1 = c4[1];   // dec0,dec1, psi0,psi1
    f32x4 v2 = c4[2];   // mc0,mc1, f0,f1
    f32x4 v3 = c4[3];   // d0,d1, pad,pad

    f32x2 dt  = {ti - v0.x,   ti - v0.y};
    f32x2 dra = {rai - v0.z,  rai - v0.w};
    f32x2 ddc = {deci - v1.x, deci - v1.y};
    f32x2 dps = {psii - v1.z, psii - v1.w};
    a_dt.x += fabsf(dt.x);   a_dt.y += fabsf(dt.y);   // abs folds into VOP3 src mod
    a_ps.x += fabsf(dps.x);  a_ps.y += fabsf(dps.y);
    a_ra.x += fabsf(dra.x);  a_ra.y += fabsf(dra.y);
    a_dc.x += fabsf(ddc.x);  a_dc.y += fabsf(ddc.y);

    f32x2 ss = dra * dra + ddc * ddc;
    a_sky.x += __builtin_amdgcn_sqrtf(ss.x);
    a_sky.y += __builtin_amdgcn_sqrtf(ss.y);

    f32x2 dm = {mci - v2.x, mci - v2.y};
    a_ms.x += __builtin_amdgcn_rcpf(1.0f + fabsf(dm.x));
    a_ms.y += __builtin_amdgcn_rcpf(1.0f + fabsf(dm.y));

    f32x2 df = {fi - v2.z, fi - v2.w};
    a_fo.x += __builtin_amdgcn_exp2f(-fabsf(df.x));   // -| | folds into v_exp src
    a_fo.y += __builtin_amdgcn_exp2f(-fabsf(df.y));

    f32x2 dd = {dsi - v3.x, dsi - v3.y};
    a_dr.x += __builtin_amdgcn_exp2f(-fabsf(dd.x));
    a_dr.y += __builtin_amdgcn_exp2f(-fabsf(dd.y));
  }

  float s0 = a_dt.x + a_dt.y;
  float s1 = a_sky.x + a_sky.y;
  float s2 = a_ms.x + a_ms.y;
  float s3 = a_fo.x + a_fo.y;
  float s4 = a_dr.x + a_dr.y;
  float s5 = a_ps.x + a_ps.y;
  float s6 = a_ra.x + a_ra.y;
  float s7 = a_dc.x + a_dc.y;

  // per-wave partials -> LDS
  float4* d = (float4*)(sacc + ((size_t)w * IB + lane) * 8);
  d[0] = make_float4(s0, s1, s2, s3);
  d[1] = make_float4(s4, s5, s6, s7);
  __syncthreads();

  // 4-way reduce + store: 512 (i,feat) values by 256 threads, coalesced
#pragma unroll
  for (int k = 0; k < 2; k++) {
    int pidx = t + k * 256;
    float v = sacc[pidx] + sacc[512 + pidx] + sacc[1024 + pidx] + sacc[1536 + pidx];
    if (PARTIAL) {
      out[((size_t)jb * N + (size_t)ib * IB) * 8 + pidx] = v;
    } else {
      atomicAdd(&out[((size_t)ib * IB) * 8 + pidx], v);
    }
  }
}

// Fused SLICES-way reduce + tiny MLP. 16 rows/block; reduction by 2 threads x 8
// feats per row; MLP by 16 threads per row (2 hidden units each, shfl LN).
template <int SLICES>
__global__ __launch_bounds__(256) void mlp_kernel(
    const float* __restrict__ X,
    const float* __restrict__ W1, const float* __restrict__ b1,
    const float* __restrict__ ln_g, const float* __restrict__ ln_b,
    const float* __restrict__ W2, const float* __restrict__ b2,
    float* __restrict__ out) {
  __shared__ float sW1[8 * 32], sW2[32 * 16];
  __shared__ float sb1[32], sg[32], sbb[32], sb2[16];
  __shared__ float sx[16 * 8];
  __shared__ float sh[16 * 32];
  __shared__ float stmp[256];
  int t = threadIdx.x;
  sW1[t] = W1[t];
  sW2[t] = W2[t];
  sW2[t + 256] = W2[t + 256];
  if (t < 32) { sb1[t] = b1[t]; sg[t] = ln_g[t]; sbb[t] = ln_b[t]; }
  if (t < 16) sb2[t] = b2[t];

  int i0 = blockIdx.x * 16;

  // ---- reduce partial[SLICES][N][8] over slices ----
  {
    int r = t >> 4;          // row 0..15
    int q = (t >> 3) & 1;    // slice-half
    int f = t & 7;           // feature
    float s = 0.f;
    if (SLICES == 1) {
      if (q == 0) s = X[(size_t)(i0 + r) * 8 + f];
    } else {
      const float* src = X + ((size_t)(q * (SLICES / 2)) * N + (i0 + r)) * 8 + f;
#pragma unroll
      for (int k = 0; k < SLICES / 2; k++) s += src[(size_t)k * N * 8];
    }
    stmp[t] = s;
    __syncthreads();
    if (q == 0) sx[r * 8 + f] = stmp[t] + stmp[t + 8];
  }
  __syncthreads();

  // ---- MLP: 16 threads per row ----
  {
    int r = t >> 4;
    int u = t & 15;
    const float diag[8] = {0.f, 0.f, 1.f, 1.f, 1.f, 0.f, 0.f, 0.f};
    const float inv_nm1 = 1.0f / (float)(N - 1);
    float x[8];
#pragma unroll
    for (int k = 0; k < 8; k++) x[k] = (sx[r * 8 + k] - diag[k]) * inv_nm1;

    int o0 = u * 2, o1 = o0 + 1;
    float h0 = sb1[o0], h1 = sb1[o1];
#pragma unroll
    for (int k = 0; k < 8; k++) {
      h0 += x[k] * sW1[k * 32 + o0];
      h1 += x[k] * sW1[k * 32 + o1];
    }

    float sum = h0 + h1;
#pragma unroll
    for (int m = 1; m < 16; m <<= 1) sum += __shfl_xor(sum, m);
    float mu = sum * (1.0f / 32.0f);
    float d0 = h0 - mu, d1 = h1 - mu;
    float vs = d0 * d0 + d1 * d1;
#pragma unroll
    for (int m = 1; m < 16; m <<= 1) vs += __shfl_xor(vs, m);
    float inv = rsqrtf(vs * (1.0f / 32.0f) + 1e-5f);

    float hn0 = d0 * inv * sg[o0] + sbb[o0];
    float hn1 = d1 * inv * sg[o1] + sbb[o1];
    float g0 = 0.5f * hn0 * (1.0f + erff(hn0 * 0.70710678118654752f));
    float g1 = 0.5f * hn1 * (1.0f + erff(hn1 * 0.70710678118654752f));
    sh[r * 32 + o0] = g0;
    sh[r * 32 + o1] = g1;
    __syncthreads();

    float a = sb2[u];
#pragma unroll
    for (int k = 0; k < 32; k++) a += sh[r * 32 + k] * sW2[k * 16 + u];
    out[(size_t)(i0 + r) * 16 + u] = a;
  }
}

extern "C" void kernel_launch(void* const* d_in, const int* in_sizes, int n_in,
                              void* d_out, int out_size, void* d_ws, size_t ws_size,
                              hipStream_t stream) {
  const float* p    = (const float*)d_in[0];
  const float* W1   = (const float*)d_in[1];
  const float* b1   = (const float*)d_in[2];
  const float* ln_g = (const float*)d_in[3];
  const float* ln_b = (const float*)d_in[4];
  const float* W2   = (const float*)d_in[5];
  const float* b2   = (const float*)d_in[6];
  float* out = (float*)d_out;
  float* ws  = (float*)d_ws;

  // workspace layout (floats):
  //   [0, 32768)        Dpair  (N/2 * 16, 128 KB)
  //   [32768, 65536)    Di     (N * 8,   128 KB)
  //   [65536, ...)      partials NJ*N*8  — or accum N*8 (fallback)
  float* Dpair = ws;
  float* Di    = ws + 32768;
  float* part  = ws + 65536;

  const size_t base    = 65536 * sizeof(float);
  const size_t need32  = base + (size_t)32 * N * 8 * sizeof(float);  // 4.25 MB
  const size_t need16  = base + (size_t)16 * N * 8 * sizeof(float);  // 2.25 MB

  derive_kernel<<<N / 256, 256, 0, stream>>>(p, Dpair, Di);

  if (ws_size >= need32) {
    dim3 grid(N / IB, 32);
    pairwise_kernel<32, true><<<grid, 256, 0, stream>>>(Dpair, Di, part);
    mlp_kernel<32><<<N / 16, 256, 0, stream>>>(part, W1, b1, ln_g, ln_b, W2, b2, out);
  } else if (ws_size >= need16) {
    dim3 grid(N / IB, 16);
    pairwise_kernel<16, true><<<grid, 256, 0, stream>>>(Dpair, Di, part);
    mlp_kernel<16><<<N / 16, 256, 0, stream>>>(part, W1, b1, ln_g, ln_b, W2, b2, out);
  } else {
    hipMemsetAsync(part, 0, (size_t)N * 8 * sizeof(float), stream);
    dim3 grid(N / IB, 32);
    pairwise_kernel<32, false><<<grid, 256, 0, stream>>>(Dpair, Di, part);
    mlp_kernel<1><<<N / 16, 256, 0, stream>>>(part, W1, b1, ln_g, ln_b, W2, b2, out);
  }
}

// Round 3
// 82.933 us; speedup vs baseline: 2.0970x; 2.0970x over previous
//
#include <hip/hip_runtime.h>
#include <math.h>

#define N        4096
#define NPARAM   15
#define ROWS     16           // i-rows per block
#define NB       (N / ROWS)   // 256 blocks (one per CU)
#define TPB      512          // 8 waves; 2 waves/SIMD
#define CHUNK    512          // j's staged per chunk
#define NCHUNK   (N / CHUNK)  // 8
#define JCG      32           // j-groups (t>>4), 32 j-columns
#define PSTRIDE  520          // words per SoA param array (512 + 8 pad -> bank rotate)

typedef float f32x2 __attribute__((ext_vector_type(2)));

// Derived per-point params (rescaled so the O(n^2) loop is minimal):
//   o0 = t, o1 = ra, o2 = dec, o3 = psi
//   o4 = mc/30                        (mass_sim = rcp(1+|d o4|))
//   o5 = 220*log2(e)/100/msum         (freq_ov  = exp2(-|d o5|))
//   o6 = log2(dist)                   (dist_rat = exp2(-|d o6|), exact)
__device__ __forceinline__ void derive_params(const float* __restrict__ r, float* o) {
  float m1 = fmaf(r[0], 95.0f, 5.0f);
  float m2 = fmaf(r[1], 95.0f, 5.0f);
  float msum = m1 + m2;
  float mc30 = __builtin_amdgcn_exp2f(
      0.6f * __builtin_amdgcn_logf(m1 * m2)
      - 0.2f * __builtin_amdgcn_logf(msum)
      - 4.906890595608519f);
  o[0] = r[5];
  o[1] = r[3];
  o[2] = r[4];
  o[3] = r[7];
  o[4] = mc30;
  o[5] = 3.1739290899556993f * __builtin_amdgcn_rcpf(msum);
  o[6] = __builtin_amdgcn_logf(fmaf(r[2], 2950.0f, 50.0f));
}

// Single fused kernel: no workspace, no atomics, one launch.
// Block = 16 rows x all 4096 j's. 512 threads: row = t&15, jc = t>>4 (32 j-cols).
// j-params derived in-block into double-buffered LDS chunks of 512 (T14 split:
// issue next chunk's global loads before compute, derive+write after).
// Epilogue: LDS reduce over 32 jc partials, then fused 16-row MLP.
__global__ __launch_bounds__(TPB, 2) void fused_kernel(
    const float* __restrict__ p,
    const float* __restrict__ W1, const float* __restrict__ b1,
    const float* __restrict__ ln_g, const float* __restrict__ ln_b,
    const float* __restrict__ W2, const float* __restrict__ b2,
    float* __restrict__ out) {
  __shared__ __align__(16) float sj[2][7 * PSTRIDE];  // SoA, double-buffered (~29 KB)
  __shared__ float sacc[JCG * ROWS * 8];              // 16 KB
  __shared__ float stmp[TPB];
  __shared__ float sx[ROWS * 8];
  __shared__ float sh[ROWS * 32];
  __shared__ float sW1[8 * 32], sW2[32 * 16];
  __shared__ float sb1[32], sg[32], sbb[32], sb2[16];

  int t   = threadIdx.x;
  int bid = blockIdx.x;
  int row = t & 15;
  int jc  = t >> 4;          // 0..31
  int i   = bid * ROWS + row;

  // stage MLP weights once (tiny)
  if (t < 256) { sW1[t] = W1[t]; sW2[t] = W2[t]; sW2[t + 256] = W2[t + 256]; }
  if (t < 32)            { sb1[t] = b1[t]; sg[t] = ln_g[t]; sbb[t] = ln_b[t]; }
  else if (t < 48)       { sb2[t - 32] = b2[t - 32]; }

  // my i-point (32 threads share a row -> L1 broadcast)
  float pi[8];
  derive_params(p + (size_t)i * NPARAM, pi);
  float ti = pi[0], rai = pi[1], deci = pi[2], psii = pi[3];
  float mci = pi[4], fi = pi[5], dsi = pi[6];

  // prologue: stage chunk 0 (thread t stages j = t)
  {
    float r[8];
    const float* pr = p + (size_t)t * NPARAM;
#pragma unroll
    for (int k = 0; k < 8; k++) r[k] = pr[k];
    float o[7];
    derive_params(r, o);
#pragma unroll
    for (int k = 0; k < 7; k++) sj[0][k * PSTRIDE + t] = o[k];  // stride-1 across lanes: conflict-free
  }
  __syncthreads();

  f32x2 a_dt = {0.f, 0.f}, a_sky = {0.f, 0.f}, a_ms = {0.f, 0.f},
        a_fo = {0.f, 0.f}, a_dr = {0.f, 0.f}, a_ps = {0.f, 0.f},
        a_ra = {0.f, 0.f}, a_dc = {0.f, 0.f};

  for (int c = 0; c < NCHUNK; c++) {
    int cur = c & 1, nxt = cur ^ 1;

    // T14: issue next chunk's global loads early (latency hides under compute)
    float rn[8];
    if (c + 1 < NCHUNK) {
      const float* pn = p + ((size_t)(c + 1) * CHUNK + t) * NPARAM;
#pragma unroll
      for (int k = 0; k < 8; k++) rn[k] = pn[k];
    }

    // compute current chunk: 8 pk-iters, 2 j's each (pair = q*32 + jc)
    const float* sb = sj[cur];
#pragma unroll
    for (int q = 0; q < CHUNK / (JCG * 2); q++) {
      int w0 = (q * JCG + jc) * 2;  // word index of the j-pair (8B aligned)
      f32x2 tj  = *(const f32x2*)(sb + 0 * PSTRIDE + w0);
      f32x2 raj = *(const f32x2*)(sb + 1 * PSTRIDE + w0);
      f32x2 dcj = *(const f32x2*)(sb + 2 * PSTRIDE + w0);
      f32x2 psj = *(const f32x2*)(sb + 3 * PSTRIDE + w0);
      f32x2 mcj = *(const f32x2*)(sb + 4 * PSTRIDE + w0);
      f32x2 fj  = *(const f32x2*)(sb + 5 * PSTRIDE + w0);
      f32x2 dj  = *(const f32x2*)(sb + 6 * PSTRIDE + w0);

      f32x2 dt  = {ti - tj.x,    ti - tj.y};
      f32x2 dra = {rai - raj.x,  rai - raj.y};
      f32x2 ddc = {deci - dcj.x, deci - dcj.y};
      f32x2 dps = {psii - psj.x, psii - psj.y};
      a_dt.x += fabsf(dt.x);   a_dt.y += fabsf(dt.y);   // abs folds into VOP3 src mod
      a_ps.x += fabsf(dps.x);  a_ps.y += fabsf(dps.y);
      a_ra.x += fabsf(dra.x);  a_ra.y += fabsf(dra.y);
      a_dc.x += fabsf(ddc.x);  a_dc.y += fabsf(ddc.y);

      f32x2 ss = dra * dra + ddc * ddc;
      a_sky.x += __builtin_amdgcn_sqrtf(ss.x);
      a_sky.y += __builtin_amdgcn_sqrtf(ss.y);

      f32x2 dm = {mci - mcj.x, mci - mcj.y};
      a_ms.x += __builtin_amdgcn_rcpf(1.0f + fabsf(dm.x));
      a_ms.y += __builtin_amdgcn_rcpf(1.0f + fabsf(dm.y));

      f32x2 df = {fi - fj.x, fi - fj.y};
      a_fo.x += __builtin_amdgcn_exp2f(-fabsf(df.x));
      a_fo.y += __builtin_amdgcn_exp2f(-fabsf(df.y));

      f32x2 dd = {dsi - dj.x, dsi - dj.y};
      a_dr.x += __builtin_amdgcn_exp2f(-fabsf(dd.x));
      a_dr.y += __builtin_amdgcn_exp2f(-fabsf(dd.y));
    }

    // derive + write next chunk (sj[nxt] free: last read before previous sync)
    if (c + 1 < NCHUNK) {
      float o[7];
      derive_params(rn, o);
#pragma unroll
      for (int k = 0; k < 7; k++) sj[nxt][k * PSTRIDE + t] = o[k];
    }
    __syncthreads();
  }

  // per-thread partials -> sacc[jc][row][8]
  {
    float s0 = a_dt.x + a_dt.y, s1 = a_sky.x + a_sky.y;
    float s2 = a_ms.x + a_ms.y, s3 = a_fo.x + a_fo.y;
    float s4 = a_dr.x + a_dr.y, s5 = a_ps.x + a_ps.y;
    float s6 = a_ra.x + a_ra.y, s7 = a_dc.x + a_dc.y;
    float4* d = (float4*)(sacc + ((size_t)jc * ROWS + row) * 8);
    d[0] = make_float4(s0, s1, s2, s3);
    d[1] = make_float4(s4, s5, s6, s7);
  }
  __syncthreads();

  // reduce 32 jc-partials for 128 (row,feat) sums: t -> (rr, ff, qq)
  {
    int rr = t >> 5, ff = (t >> 2) & 7, qq = t & 3;
    float s = 0.f;
#pragma unroll
    for (int k = 0; k < 8; k++) s += sacc[((qq * 8 + k) * ROWS + rr) * 8 + ff];
    stmp[t] = s;
    __syncthreads();
    if (qq == 0) sx[rr * 8 + ff] = stmp[t] + stmp[t + 1] + stmp[t + 2] + stmp[t + 3];
  }
  __syncthreads();

  // fused MLP: 16 threads per row (threads 0..255)
  int rm = t >> 4, u = t & 15;
  if (t < 256) {
    const float diag[8] = {0.f, 0.f, 1.f, 1.f, 1.f, 0.f, 0.f, 0.f};
    const float inv_nm1 = 1.0f / (float)(N - 1);
    float x[8];
#pragma unroll
    for (int k = 0; k < 8; k++) x[k] = (sx[rm * 8 + k] - diag[k]) * inv_nm1;

    int o0 = u * 2, o1 = o0 + 1;
    float h0 = sb1[o0], h1 = sb1[o1];
#pragma unroll
    for (int k = 0; k < 8; k++) {
      h0 += x[k] * sW1[k * 32 + o0];
      h1 += x[k] * sW1[k * 32 + o1];
    }

    float sum = h0 + h1;
#pragma unroll
    for (int m = 1; m < 16; m <<= 1) sum += __shfl_xor(sum, m);
    float mu = sum * (1.0f / 32.0f);
    float d0 = h0 - mu, d1 = h1 - mu;
    float vs = d0 * d0 + d1 * d1;
#pragma unroll
    for (int m = 1; m < 16; m <<= 1) vs += __shfl_xor(vs, m);
    float inv = rsqrtf(vs * (1.0f / 32.0f) + 1e-5f);

    float hn0 = d0 * inv * sg[o0] + sbb[o0];
    float hn1 = d1 * inv * sg[o1] + sbb[o1];
    float g0 = 0.5f * hn0 * (1.0f + erff(hn0 * 0.70710678118654752f));
    float g1 = 0.5f * hn1 * (1.0f + erff(hn1 * 0.70710678118654752f));
    sh[rm * 32 + o0] = g0;
    sh[rm * 32 + o1] = g1;
  }
  __syncthreads();
  if (t < 256) {
    float a = sb2[u];
#pragma unroll
    for (int k = 0; k < 32; k++) a += sh[rm * 32 + k] * sW2[k * 16 + u];
    out[(size_t)(bid * ROWS + rm) * 16 + u] = a;
  }
}

extern "C" void kernel_launch(void* const* d_in, const int* in_sizes, int n_in,
                              void* d_out, int out_size, void* d_ws, size_t ws_size,
                              hipStream_t stream) {
  const float* p    = (const float*)d_in[0];
  const float* W1   = (const float*)d_in[1];
  const float* b1   = (const float*)d_in[2];
  const float* ln_g = (const float*)d_in[3];
  const float* ln_b = (const float*)d_in[4];
  const float* W2   = (const float*)d_in[5];
  const float* b2   = (const float*)d_in[6];
  float* out = (float*)d_out;
  (void)d_ws; (void)ws_size;

  fused_kernel<<<NB, TPB, 0, stream>>>(p, W1, b1, ln_g, ln_b, W2, b2, out);
}